// Round 3
// baseline (98.292 us; speedup 1.0000x reference)
//
#include <hip/hip_runtime.h>

#define B_ 32
#define N_ 4096
#define M_ 32
#define F_ 256
#define A_ 8

typedef float f32x4 __attribute__((ext_vector_type(4)));

// workspace layout (floats):
//   [0, 256)                      wv  = W @ (a1+a2)
//   [256, 256 + B*A*F)            anchor_feat  (B,A,F)
//   [256 + B*A*F, +B*A)           e2  = anchor_feat @ (a1-a2)
#define WS_WV 0
#define WS_AF 256
#define WS_E2 (256 + B_ * A_ * F_)

// ---- kernel 0: wv[i] = sum_f W[i,f] * (a[f] + a[f+F]) ------------------
__global__ __launch_bounds__(256) void wv_kernel(const float* __restrict__ W,
                                                 const float* __restrict__ a,
                                                 float* __restrict__ ws) {
    __shared__ float as_[F_];
    int t = threadIdx.x;
    as_[t] = a[t] + a[t + F_];
    __syncthreads();
    float acc = 0.f;
    const float* wrow = W + t * F_;
#pragma unroll 8
    for (int f = 0; f < F_; ++f) acc += wrow[f] * as_[f];
    ws[WS_WV + t] = acc;
}

// ---- kernel 1: anchor_feat[b,k,:] = fatoms[b, idx[b,k], :] @ W ; e2 ----
__global__ __launch_bounds__(256) void anchor_kernel(const float* __restrict__ fatoms,
                                                     const int* __restrict__ anchor_idx,
                                                     const float* __restrict__ W,
                                                     const float* __restrict__ a,
                                                     float* __restrict__ ws) {
    int bk = blockIdx.x;  // b*A_ + k
    int b  = bk / A_;
    int f  = threadIdx.x;
    __shared__ float xs[F_];
    __shared__ float red[F_];
    int idx = anchor_idx[bk];
    xs[f] = fatoms[((size_t)b * N_ + idx) * F_ + f];
    __syncthreads();
    float acc = 0.f;
#pragma unroll 8
    for (int i = 0; i < F_; ++i) acc += xs[i] * W[i * F_ + f];  // coalesced over f
    ws[WS_AF + bk * F_ + f] = acc;
    red[f] = acc * (a[f] - a[f + F_]);
    __syncthreads();
    for (int s = 128; s > 0; s >>= 1) {
        if (f < s) red[f] += red[f + s];
        __syncthreads();
    }
    if (f == 0) ws[WS_E2 + bk] = red[0];
}

// ---- kernel 2: main streaming kernel ----------------------------------
// Half-wave per row: lanes 0-31 own row 2p, lanes 32-63 own row 2p+1.
// Each lane covers features [sub*8, sub*8+8). 4 row-pairs (8 rows) in
// flight per chunk for ILP; 2 chunks = 16 rows per wave.
#define RPW 16  // rows per wave
#define WPB 4   // waves per block
#define UP 4    // row-pairs in flight per chunk

__global__ __launch_bounds__(256) void main_kernel(const float* __restrict__ fatoms,
                                                   const int* __restrict__ agraph,
                                                   const int* __restrict__ anchor_idx,
                                                   const float* __restrict__ ws,
                                                   float* __restrict__ out) {
    int tid  = threadIdx.x;
    int wave = tid >> 6, lane = tid & 63;
    int half = lane >> 5;   // 0: even row of pair, 1: odd row
    int sub  = lane & 31;   // feature-group / agraph index
    const int rows_per_block   = WPB * RPW;            // 64
    const int blocks_per_batch = N_ / rows_per_block;  // 64
    int b     = blockIdx.x / blocks_per_batch;
    int chunk = blockIdx.x % blocks_per_batch;
    int row0  = chunk * rows_per_block + wave * RPW;

    const float* wv = ws + WS_WV;
    const float* af = ws + WS_AF + b * (A_ * F_);
    const float* e2 = ws + WS_E2 + b * A_;

    // anchor_feat for this batch -> LDS (shared by all 4 waves; same b)
    __shared__ float af_lds[A_ * F_];
    {
        f32x4*       dst = (f32x4*)af_lds;
        const f32x4* src = (const f32x4*)af;
        dst[tid]       = src[tid];
        dst[tid + 256] = src[tid + 256];
    }

    // uniform per-block scalars
    float e2r[A_];
    int   anch[A_];
#pragma unroll
    for (int k = 0; k < A_; ++k) {
        e2r[k]  = e2[k];
        anch[k] = anchor_idx[b * A_ + k];
    }

    // wv fragment for this lane's 8 features
    float wvr[8];
    {
        f32x4 t0 = *(const f32x4*)(wv + sub * 8);
        f32x4 t1 = *(const f32x4*)(wv + sub * 8 + 4);
        wvr[0] = t0.x; wvr[1] = t0.y; wvr[2] = t0.z; wvr[3] = t0.w;
        wvr[4] = t1.x; wvr[5] = t1.y; wvr[6] = t1.z; wvr[7] = t1.w;
    }
    __syncthreads();

    for (int c = 0; c < RPW / (2 * UP); ++c) {
        int p0 = c * UP;  // first pair of this chunk

        // ---- issue all global loads for UP pairs up front ----
        float x[UP][8];
        int   g[UP];
#pragma unroll
        for (int u = 0; u < UP; ++u) {
            int    r      = row0 + (p0 + u) * 2 + half;
            size_t rowoff = (size_t)b * N_ + r;
            const float* rp = fatoms + rowoff * F_ + sub * 8;
            f32x4 t0 = *(const f32x4*)rp;
            f32x4 t1 = *(const f32x4*)(rp + 4);
            x[u][0] = t0.x; x[u][1] = t0.y; x[u][2] = t0.z; x[u][3] = t0.w;
            x[u][4] = t1.x; x[u][5] = t1.y; x[u][6] = t1.z; x[u][7] = t1.w;
            g[u] = agraph[rowoff * M_ + sub];
        }

        // ---- partial dots ----
        float d[UP];
#pragma unroll
        for (int u = 0; u < UP; ++u) {
            float acc = 0.f;
#pragma unroll
            for (int j = 0; j < 8; ++j) acc += x[u][j] * wvr[j];
            d[u] = acc;
        }

        // ---- 5-step butterfly within each 32-lane half (4 indep chains) ----
#pragma unroll
        for (int off = 16; off > 0; off >>= 1) {
#pragma unroll
            for (int u = 0; u < UP; ++u) d[u] += __shfl_xor(d[u], off);
        }

        // ---- per-row mask, softmax, weighted anchor sum, store ----
#pragma unroll
        for (int u = 0; u < UP; ++u) {
            int    r      = row0 + (p0 + u) * 2 + half;
            size_t rowoff = (size_t)b * N_ + r;

            float ek[A_];
#pragma unroll
            for (int k = 0; k < A_; ++k) {
                unsigned long long bal = __ballot(g[u] == anch[k]);
                unsigned int lo = (unsigned int)bal;
                unsigned int hi = (unsigned int)(bal >> 32);
                unsigned int my = half ? hi : lo;
                ek[k] = my ? (d[u] + e2r[k]) : -1.0e9f;
            }

            float m = ek[0];
#pragma unroll
            for (int k = 1; k < A_; ++k) m = fmaxf(m, ek[k]);
            float s = 0.f, p[A_];
#pragma unroll
            for (int k = 0; k < A_; ++k) { p[k] = __expf(ek[k] - m); s += p[k]; }
            float rinv = __builtin_amdgcn_rcpf(s);

            float o[8];
#pragma unroll
            for (int j = 0; j < 8; ++j) o[j] = 0.f;
#pragma unroll
            for (int k = 0; k < A_; ++k) {
                float w = p[k] * rinv;
                const float* afp = af_lds + k * F_ + sub * 8;
#pragma unroll
                for (int j = 0; j < 8; ++j) o[j] += w * afp[j];
            }

            float* op = out + rowoff * F_ + sub * 8;
            f32x4 o0 = {o[0], o[1], o[2], o[3]};
            f32x4 o1 = {o[4], o[5], o[6], o[7]};
            __builtin_nontemporal_store(o0, (f32x4*)op);
            __builtin_nontemporal_store(o1, (f32x4*)(op + 4));
        }
    }
}

extern "C" void kernel_launch(void* const* d_in, const int* in_sizes, int n_in,
                              void* d_out, int out_size, void* d_ws, size_t ws_size,
                              hipStream_t stream) {
    const float* fatoms     = (const float*)d_in[0];
    const int*   agraph     = (const int*)d_in[1];
    const int*   anchor_idx = (const int*)d_in[2];
    const float* W          = (const float*)d_in[3];
    const float* a          = (const float*)d_in[4];
    float*       out        = (float*)d_out;
    float*       ws         = (float*)d_ws;

    hipLaunchKernelGGL(wv_kernel, dim3(1), dim3(256), 0, stream, W, a, ws);
    hipLaunchKernelGGL(anchor_kernel, dim3(B_ * A_), dim3(256), 0, stream,
                       fatoms, anchor_idx, W, a, ws);
    hipLaunchKernelGGL(main_kernel, dim3(B_ * (N_ / (WPB * RPW))), dim3(256), 0, stream,
                       fatoms, agraph, anchor_idx, ws, out);
}

// Round 4
// 72.638 us; speedup vs baseline: 1.3532x; 1.3532x over previous
//
#include <hip/hip_runtime.h>

#define B_ 32
#define N_ 4096
#define M_ 32
#define F_ 256
#define A_ 8

typedef float f32x4 __attribute__((ext_vector_type(4)));

// workspace layout (floats):
//   [0, 256)                      wv  = W @ (a1+a2)
//   [256, 256 + B*A*F)            anchor_feat  (B,A,F)
//   [256 + B*A*F, +B*A)           e2  = anchor_feat @ (a1-a2)
#define WS_WV 0
#define WS_AF 256
#define WS_E2 (256 + B_ * A_ * F_)

// ---- kernel 0: wv[i] = sum_f W[i,f] * (a[f] + a[f+F]) ------------------
__global__ __launch_bounds__(256) void wv_kernel(const float* __restrict__ W,
                                                 const float* __restrict__ a,
                                                 float* __restrict__ ws) {
    __shared__ float as_[F_];
    int t = threadIdx.x;
    as_[t] = a[t] + a[t + F_];
    __syncthreads();
    float acc = 0.f;
    const float* wrow = W + t * F_;
#pragma unroll 8
    for (int f = 0; f < F_; ++f) acc += wrow[f] * as_[f];
    ws[WS_WV + t] = acc;
}

// ---- kernel 1: anchor_feat[b,k,:] = fatoms[b, idx[b,k], :] @ W ; e2 ----
__global__ __launch_bounds__(256) void anchor_kernel(const float* __restrict__ fatoms,
                                                     const int* __restrict__ anchor_idx,
                                                     const float* __restrict__ W,
                                                     const float* __restrict__ a,
                                                     float* __restrict__ ws) {
    int bk = blockIdx.x;  // b*A_ + k
    int b  = bk / A_;
    int f  = threadIdx.x;
    __shared__ float xs[F_];
    __shared__ float red[F_];
    int idx = anchor_idx[bk];
    xs[f] = fatoms[((size_t)b * N_ + idx) * F_ + f];
    __syncthreads();
    float acc = 0.f;
#pragma unroll 8
    for (int i = 0; i < F_; ++i) acc += xs[i] * W[i * F_ + f];  // coalesced over f
    ws[WS_AF + bk * F_ + f] = acc;
    red[f] = acc * (a[f] - a[f + F_]);
    __syncthreads();
    for (int s = 128; s > 0; s >>= 1) {
        if (f < s) red[f] += red[f + s];
        __syncthreads();
    }
    if (f == 0) ws[WS_E2 + bk] = red[0];
}

// ---- kernel 2: main streaming kernel ----------------------------------
// Whole wave per row (R1 layout: contiguous 1KB per load/store instr),
// UP rows in flight for load-latency pipelining.
#define RPW 16  // rows per wave
#define WPB 4   // waves per block
#define UP 4    // rows in flight

__global__ __launch_bounds__(256) void main_kernel(const float* __restrict__ fatoms,
                                                   const int* __restrict__ agraph,
                                                   const int* __restrict__ anchor_idx,
                                                   const float* __restrict__ ws,
                                                   float* __restrict__ out) {
    int tid  = threadIdx.x;
    int wave = tid >> 6, lane = tid & 63;
    const int rows_per_block   = WPB * RPW;            // 64
    const int blocks_per_batch = N_ / rows_per_block;  // 64
    int b     = blockIdx.x / blocks_per_batch;
    int chunk = blockIdx.x % blocks_per_batch;
    int row0  = chunk * rows_per_block + wave * RPW;

    const float* wv = ws + WS_WV;
    const float* af = ws + WS_AF + b * (A_ * F_);
    const float* e2 = ws + WS_E2 + b * A_;

    // per-wave constants: wv fragment, anchor_feat fragments, e2, anchor ids
    f32x4 wvr = *(const f32x4*)(wv + lane * 4);
    f32x4 afr[A_];
    float e2r[A_];
    int   anch[A_];
#pragma unroll
    for (int k = 0; k < A_; ++k) {
        afr[k]  = *(const f32x4*)(af + k * F_ + lane * 4);
        e2r[k]  = e2[k];
        anch[k] = anchor_idx[b * A_ + k];
    }

    for (int c = 0; c < RPW / UP; ++c) {
        // ---- issue all global loads for UP rows up front ----
        f32x4 x[UP];
        int   g[UP];
#pragma unroll
        for (int u = 0; u < UP; ++u) {
            int    n      = row0 + c * UP + u;
            size_t rowoff = (size_t)b * N_ + n;
            x[u] = *(const f32x4*)(fatoms + rowoff * F_ + lane * 4);
            g[u] = agraph[rowoff * M_ + (lane & (M_ - 1))];
        }

        // ---- partial dots (independent) ----
        float d[UP];
#pragma unroll
        for (int u = 0; u < UP; ++u)
            d[u] = x[u].x * wvr.x + x[u].y * wvr.y + x[u].z * wvr.z + x[u].w * wvr.w;

        // ---- 6-step butterfly, UP independent chains interleaved ----
#pragma unroll
        for (int off = 32; off > 0; off >>= 1) {
#pragma unroll
            for (int u = 0; u < UP; ++u) d[u] += __shfl_xor(d[u], off);
        }

        // ---- per-row mask, softmax, weighted anchor sum, store ----
#pragma unroll
        for (int u = 0; u < UP; ++u) {
            int    n      = row0 + c * UP + u;
            size_t rowoff = (size_t)b * N_ + n;

            float ek[A_];
#pragma unroll
            for (int k = 0; k < A_; ++k)
                ek[k] = __any(g[u] == anch[k]) ? (d[u] + e2r[k]) : -1.0e9f;

            float m = ek[0];
#pragma unroll
            for (int k = 1; k < A_; ++k) m = fmaxf(m, ek[k]);
            float s = 0.f, p[A_];
#pragma unroll
            for (int k = 0; k < A_; ++k) { p[k] = __expf(ek[k] - m); s += p[k]; }
            float rinv = __builtin_amdgcn_rcpf(s);

            f32x4 o = {0.f, 0.f, 0.f, 0.f};
#pragma unroll
            for (int k = 0; k < A_; ++k) {
                float w = p[k] * rinv;
                o.x += w * afr[k].x;
                o.y += w * afr[k].y;
                o.z += w * afr[k].z;
                o.w += w * afr[k].w;
            }
            __builtin_nontemporal_store(o, (f32x4*)(out + rowoff * F_ + lane * 4));
        }
    }
}

extern "C" void kernel_launch(void* const* d_in, const int* in_sizes, int n_in,
                              void* d_out, int out_size, void* d_ws, size_t ws_size,
                              hipStream_t stream) {
    const float* fatoms     = (const float*)d_in[0];
    const int*   agraph     = (const int*)d_in[1];
    const int*   anchor_idx = (const int*)d_in[2];
    const float* W          = (const float*)d_in[3];
    const float* a          = (const float*)d_in[4];
    float*       out        = (float*)d_out;
    float*       ws         = (float*)d_ws;

    hipLaunchKernelGGL(wv_kernel, dim3(1), dim3(256), 0, stream, W, a, ws);
    hipLaunchKernelGGL(anchor_kernel, dim3(B_ * A_), dim3(256), 0, stream,
                       fatoms, anchor_idx, W, a, ws);
    hipLaunchKernelGGL(main_kernel, dim3(B_ * (N_ / (WPB * RPW))), dim3(256), 0, stream,
                       fatoms, agraph, anchor_idx, ws, out);
}

// Round 5
// 39.795 us; speedup vs baseline: 2.4700x; 1.8253x over previous
//
#include <hip/hip_runtime.h>

#define B_ 32
#define N_ 4096
#define M_ 32
#define F_ 256
#define A_ 8

typedef float f32x4 __attribute__((ext_vector_type(4)));
typedef int   i32x4 __attribute__((ext_vector_type(4)));

// workspace layout (floats):
//   [0, B*A*F)        anchor_feat  (B,A,F)
//   [B*A*F, +B*A)     e2 = anchor_feat @ (a1-a2)
#define WS_AF 0
#define WS_E2 (B_ * A_ * F_)

// ---- kernel 1: anchor_feat[b,k,:] = fatoms[b, idx[b,k], :] @ W ; e2 ----
// NOTE: e1 = h@(a1+a2) is provably irrelevant: e[b,n,k] = e1[b,n] + e2[b,k],
// softmax over k is invariant to the per-row constant e1 (masked entries are
// -1e9 absolute; exp underflows to 0 either way; all-masked -> uniform 1/8).
// So fatoms is only ever read for the A=8 anchor rows per batch.
__global__ __launch_bounds__(256) void anchor_kernel(const float* __restrict__ fatoms,
                                                     const int* __restrict__ anchor_idx,
                                                     const float* __restrict__ W,
                                                     const float* __restrict__ a,
                                                     float* __restrict__ ws) {
    int bk = blockIdx.x;  // b*A_ + k
    int b  = bk / A_;
    int f  = threadIdx.x;
    __shared__ float xs[F_];
    __shared__ float red[F_];
    int idx = anchor_idx[bk];
    xs[f] = fatoms[((size_t)b * N_ + idx) * F_ + f];
    __syncthreads();
    float acc = 0.f;
#pragma unroll 8
    for (int i = 0; i < F_; ++i) acc += xs[i] * W[i * F_ + f];  // coalesced over f
    ws[WS_AF + bk * F_ + f] = acc;
    red[f] = acc * (a[f] - a[f + F_]);
    __syncthreads();
    for (int s = 128; s > 0; s >>= 1) {
        if (f < s) red[f] += red[f + s];
        __syncthreads();
    }
    if (f == 0) ws[WS_E2 + bk] = red[0];
}

// ---- kernel 2: main kernel — agraph in, out written; no fatoms ---------
#define WPB 4   // waves per block
#define RPW 32  // rows per wave; phase 1: lanes 0..31 own one row each

__global__ __launch_bounds__(256) void main_kernel(const int* __restrict__ agraph,
                                                   const int* __restrict__ anchor_idx,
                                                   const float* __restrict__ ws,
                                                   float* __restrict__ out) {
    int tid  = threadIdx.x;
    int wave = tid >> 6, lane = tid & 63;
    const int rows_per_block   = WPB * RPW;            // 128
    const int blocks_per_batch = N_ / rows_per_block;  // 32
    int b     = blockIdx.x / blocks_per_batch;
    int chunk = blockIdx.x % blocks_per_batch;
    int row0  = chunk * rows_per_block + wave * RPW;

    const float* af = ws + WS_AF + b * (A_ * F_);
    const float* e2 = ws + WS_E2 + b * A_;

    __shared__ float attn[WPB][RPW][A_];

    // per-batch uniforms
    int   anch[A_];
    float e2r[A_];
#pragma unroll
    for (int k = 0; k < A_; ++k) {
        anch[k] = anchor_idx[b * A_ + k];
        e2r[k]  = e2[k];
    }
    // E_k = exp(e2_k - max_k e2)  (shared shift; masked-softmax ratios exact)
    float m8 = e2r[0];
#pragma unroll
    for (int k = 1; k < A_; ++k) m8 = fmaxf(m8, e2r[k]);
    float E[A_];
#pragma unroll
    for (int k = 0; k < A_; ++k) E[k] = __expf(e2r[k] - m8);

    // anchor_feat fragment for this lane's 4 features
    f32x4 afr[A_];
#pragma unroll
    for (int k = 0; k < A_; ++k) afr[k] = *(const f32x4*)(af + k * F_ + lane * 4);

    // ---- phase 1: one row per lane (lanes 0..31) ----
    if (lane < RPW) {
        int row = row0 + lane;
        const i32x4* gp = (const i32x4*)(agraph + ((size_t)b * N_ + row) * M_);
        unsigned mk = 0;
#pragma unroll
        for (int j = 0; j < M_ / 4; ++j) {
            i32x4 g = gp[j];
#pragma unroll
            for (int k = 0; k < A_; ++k) {
                int hit = (g.x == anch[k]) | (g.y == anch[k]) |
                          (g.z == anch[k]) | (g.w == anch[k]);
                mk |= hit ? (1u << k) : 0u;
            }
        }
        float p[A_], s = 0.f;
#pragma unroll
        for (int k = 0; k < A_; ++k) { p[k] = (mk & (1u << k)) ? E[k] : 0.f; s += p[k]; }
        if (mk == 0) {  // all masked -> uniform
#pragma unroll
            for (int k = 0; k < A_; ++k) p[k] = 1.f;
            s = 8.f;
        }
        float rinv = __builtin_amdgcn_rcpf(s);
#pragma unroll
        for (int k = 0; k < A_; ++k) attn[wave][lane][k] = p[k] * rinv;
    }
    __syncthreads();

    // ---- phase 2: wave cooperatively writes its 32 rows (1KB/row) ----
    size_t base = ((size_t)b * N_ + row0) * F_ + lane * 4;
    for (int r = 0; r < RPW; ++r) {
        f32x4 pa = *(const f32x4*)&attn[wave][r][0];  // broadcast reads
        f32x4 pb = *(const f32x4*)&attn[wave][r][4];
        f32x4 o = pa.x * afr[0];
        o += pa.y * afr[1];
        o += pa.z * afr[2];
        o += pa.w * afr[3];
        o += pb.x * afr[4];
        o += pb.y * afr[5];
        o += pb.z * afr[6];
        o += pb.w * afr[7];
        __builtin_nontemporal_store(o, (f32x4*)(out + base + (size_t)r * F_));
    }
}

extern "C" void kernel_launch(void* const* d_in, const int* in_sizes, int n_in,
                              void* d_out, int out_size, void* d_ws, size_t ws_size,
                              hipStream_t stream) {
    const float* fatoms     = (const float*)d_in[0];
    const int*   agraph     = (const int*)d_in[1];
    const int*   anchor_idx = (const int*)d_in[2];
    const float* W          = (const float*)d_in[3];
    const float* a          = (const float*)d_in[4];
    float*       out        = (float*)d_out;
    float*       ws         = (float*)d_ws;

    hipLaunchKernelGGL(anchor_kernel, dim3(B_ * A_), dim3(256), 0, stream,
                       fatoms, anchor_idx, W, a, ws);
    hipLaunchKernelGGL(main_kernel, dim3(B_ * (N_ / (WPB * RPW))), dim3(256), 0, stream,
                       agraph, anchor_idx, ws, out);
}

// Round 6
// 38.061 us; speedup vs baseline: 2.5825x; 1.0456x over previous
//
#include <hip/hip_runtime.h>

#define B_ 32
#define N_ 4096
#define M_ 32
#define F_ 256
#define A_ 8

typedef float f32x4 __attribute__((ext_vector_type(4)));
typedef int   i32x4 __attribute__((ext_vector_type(4)));

// workspace layout (floats):
//   [0, B*A*F)        anchor_feat  (B,A,F)
//   [B*A*F, +B*A)     e2 = anchor_feat @ (a1-a2)
#define WS_AF 0
#define WS_E2 (B_ * A_ * F_)

// ---- kernel 1: anchor_feat[b,k,:] = fatoms[b, idx[b,k], :] @ W ; e2 ----
// e1 = h@(a1+a2) is provably irrelevant: e[b,n,k] = e1[b,n] + e2[b,k] and
// softmax over k is invariant to the per-row constant e1 (masked entries are
// -1e9 absolute; exp underflows to 0 either way; all-masked -> uniform 1/8).
// So fatoms is only ever read for the A=8 anchor rows per batch.
__global__ __launch_bounds__(256) void anchor_kernel(const float* __restrict__ fatoms,
                                                     const int* __restrict__ anchor_idx,
                                                     const float* __restrict__ W,
                                                     const float* __restrict__ a,
                                                     float* __restrict__ ws) {
    int bk = blockIdx.x;  // b*A_ + k
    int b  = bk / A_;
    int f  = threadIdx.x;
    __shared__ float xs[F_];
    __shared__ float red[F_];
    int idx = anchor_idx[bk];
    xs[f] = fatoms[((size_t)b * N_ + idx) * F_ + f];
    __syncthreads();
    float acc = 0.f;
#pragma unroll 8
    for (int i = 0; i < F_; ++i) acc += xs[i] * W[i * F_ + f];  // coalesced over f
    ws[WS_AF + bk * F_ + f] = acc;
    red[f] = acc * (a[f] - a[f + F_]);
    __syncthreads();
    for (int s = 128; s > 0; s >>= 1) {
        if (f < s) red[f] += red[f + s];
        __syncthreads();
    }
    if (f == 0) ws[WS_E2 + bk] = red[0];
}

// ---- kernel 2: main kernel — 1 wave per block, 32 rows per wave --------
#define RPW 32

__global__ __launch_bounds__(64) void main_kernel(const int* __restrict__ agraph,
                                                  const int* __restrict__ anchor_idx,
                                                  const float* __restrict__ ws,
                                                  float* __restrict__ out) {
    int lane = threadIdx.x;
    const int chunks_per_batch = N_ / RPW;  // 128
    int b     = blockIdx.x / chunks_per_batch;
    int chunk = blockIdx.x % chunks_per_batch;
    int row0  = chunk * RPW;

    const float* af = ws + WS_AF + b * (A_ * F_);
    const float* e2 = ws + WS_E2 + b * A_;

    __shared__ float attn[RPW][A_];

    // per-batch uniforms
    int   anch[A_];
    float e2r[A_];
#pragma unroll
    for (int k = 0; k < A_; ++k) {
        anch[k] = anchor_idx[b * A_ + k];
        e2r[k]  = e2[k];
    }
    // E_k = exp(e2_k - max_k e2)  (shared shift; masked-softmax ratios exact)
    float m8 = e2r[0];
#pragma unroll
    for (int k = 1; k < A_; ++k) m8 = fmaxf(m8, e2r[k]);
    float E[A_];
#pragma unroll
    for (int k = 0; k < A_; ++k) E[k] = __expf(e2r[k] - m8);

    // anchor_feat fragment for this lane's 4 features
    f32x4 afr[A_];
#pragma unroll
    for (int k = 0; k < A_; ++k) afr[k] = *(const f32x4*)(af + k * F_ + lane * 4);

    // ---- phase 1: one row per lane (lanes 0..31) ----
    if (lane < RPW) {
        int row = row0 + lane;
        const i32x4* gp = (const i32x4*)(agraph + ((size_t)b * N_ + row) * M_);
        unsigned mk = 0;
#pragma unroll
        for (int j = 0; j < M_ / 4; ++j) {
            i32x4 g = gp[j];
#pragma unroll
            for (int k = 0; k < A_; ++k) {
                int hit = (g.x == anch[k]) | (g.y == anch[k]) |
                          (g.z == anch[k]) | (g.w == anch[k]);
                mk |= hit ? (1u << k) : 0u;
            }
        }
        float p[A_], s = 0.f;
#pragma unroll
        for (int k = 0; k < A_; ++k) { p[k] = (mk & (1u << k)) ? E[k] : 0.f; s += p[k]; }
        if (mk == 0) {  // all masked -> uniform
#pragma unroll
            for (int k = 0; k < A_; ++k) p[k] = 1.f;
            s = 8.f;
        }
        float rinv = __builtin_amdgcn_rcpf(s);
#pragma unroll
        for (int k = 0; k < A_; ++k) attn[lane][k] = p[k] * rinv;
    }
    __syncthreads();  // single-wave block: compiles to cheap wait+barrier

    // ---- phase 2: wave writes its 32 rows (1KB/row), 4 rows in flight ----
    size_t base = ((size_t)b * N_ + row0) * F_ + lane * 4;
    for (int r0 = 0; r0 < RPW; r0 += 4) {
        f32x4 o[4];
#pragma unroll
        for (int u = 0; u < 4; ++u) {
            f32x4 pa = *(const f32x4*)&attn[r0 + u][0];  // broadcast reads
            f32x4 pb = *(const f32x4*)&attn[r0 + u][4];
            f32x4 t = pa.x * afr[0];
            t += pa.y * afr[1];
            t += pa.z * afr[2];
            t += pa.w * afr[3];
            t += pb.x * afr[4];
            t += pb.y * afr[5];
            t += pb.z * afr[6];
            t += pb.w * afr[7];
            o[u] = t;
        }
#pragma unroll
        for (int u = 0; u < 4; ++u)
            __builtin_nontemporal_store(o[u], (f32x4*)(out + base + (size_t)(r0 + u) * F_));
    }
}

extern "C" void kernel_launch(void* const* d_in, const int* in_sizes, int n_in,
                              void* d_out, int out_size, void* d_ws, size_t ws_size,
                              hipStream_t stream) {
    const float* fatoms     = (const float*)d_in[0];
    const int*   agraph     = (const int*)d_in[1];
    const int*   anchor_idx = (const int*)d_in[2];
    const float* W          = (const float*)d_in[3];
    const float* a          = (const float*)d_in[4];
    float*       out        = (float*)d_out;
    float*       ws         = (float*)d_ws;

    hipLaunchKernelGGL(anchor_kernel, dim3(B_ * A_), dim3(256), 0, stream,
                       fatoms, anchor_idx, W, a, ws);
    hipLaunchKernelGGL(main_kernel, dim3(B_ * (N_ / RPW)), dim3(64), 0, stream,
                       agraph, anchor_idx, ws, out);
}